// Round 10
// baseline (872.877 us; speedup 1.0000x reference)
//
#include <hip/hip_runtime.h>
#include <hip/hip_cooperative_groups.h>

namespace cg = cooperative_groups;

#define CH 128
#define OUTC 10
#define NB2 512           // buckets (dst >> 8)
#define BSHIFT 8
#define BCAP2 5120        // per-bucket pair capacity (avg ~4096, +16 sigma margin)
#define PCHUNK 2048       // edges per partition block-iteration
#define PQ2 132           // LDS pitch in bf16 (dword stride 66 -> 2-way bank alias = free)
#define FBM 64            // rows per fused-layer tile
#define TPB 512

typedef __attribute__((ext_vector_type(8))) short short8;
typedef __attribute__((ext_vector_type(4))) short short4v;
typedef __attribute__((ext_vector_type(16))) float f32x16;
typedef __attribute__((ext_vector_type(2))) float f32x2;

// ---------------------------------------------------------------- helpers

__device__ inline unsigned short f2bf(float f) {
    unsigned u = __builtin_bit_cast(unsigned, f);
    u += 0x7fffu + ((u >> 16) & 1u);   // RNE
    return (unsigned short)(u >> 16);
}
__device__ inline float bflo(unsigned u) { return __builtin_bit_cast(float, u << 16); }
__device__ inline float bfhi(unsigned u) { return __builtin_bit_cast(float, u & 0xffff0000u); }

__device__ inline f32x2 bf2(unsigned u) {
    return (f32x2){__builtin_bit_cast(float, u << 16),
                   __builtin_bit_cast(float, u & 0xffff0000u)};
}

__device__ inline void acc8(f32x2* a, const uint4& v) {
    a[0] += bf2(v.x);
    a[1] += bf2(v.y);
    a[2] += bf2(v.z);
    a[3] += bf2(v.w);
}

// ---------------------------------------------------------------- mega kernel params

struct MegaP {
    const int* src; const int* dst; int E;
    int* bucketCnt; unsigned* pairs;
    int* offs; int* csr; int N;
    const float4* x4; unsigned short* xb; int n4;
    const float* wsrc[6]; unsigned short* wdst[6];
    const float* b1v[3]; const float* b2v[3];
    unsigned short* hA; unsigned short* hB;
    const int* batch; float* pooled; int nPooled4;
    int nGraphs; const float* lin_w; const float* lin_b; float* out;
};

// ---------------------------------------------------------------- mega kernel
// Phases (grid.sync between; device-scope fence handles cross-XCD L2):
//  0: edge partition (grid-stride chunks) || weight swizzle + pooled zero
//  A: CSR build (grid-stride buckets)     || x -> bf16 conversion
//  B/C/D: fused GIN layers (grid-stride 64-row tiles; R9 tile body verbatim)
//  E: final linear
// All phase work is grid-size-agnostic; barriers are block-local except the
// grid.sync boundaries, which every block reaches unconditionally (no early
// returns anywhere).

__launch_bounds__(TPB, 8)
__global__ void mega_kernel(MegaP P) {
    cg::grid_group gg = cg::this_grid();
    __shared__ __align__(16) int smem[6912];   // 27.6 KB union: partition/csr/zs/pl

    int tid = threadIdx.x;
    int b = blockIdx.x;
    int grid = (int)gridDim.x;

    // ---------------- phase 0: edge partition || wswz + pooled zero
    int nPartBlk = (P.E + PCHUNK - 1) / PCHUNK;
    for (int pb = b; pb < nPartBlk; pb += grid) {
        int* hist = smem;              // [NB2]
        int* base = smem + NB2;        // [NB2]
        int* cur  = smem + 2 * NB2;    // [NB2]
        int e0 = pb * PCHUNK;
        hist[tid] = 0;
        __syncthreads();
        #pragma unroll
        for (int i = 0; i < PCHUNK / TPB; ++i) {
            int e = e0 + tid + i * TPB;
            if (e < P.E) atomicAdd(&hist[P.dst[e] >> BSHIFT], 1);
        }
        __syncthreads();
        {
            int c = hist[tid];
            base[tid] = (c > 0) ? atomicAdd(&P.bucketCnt[tid], c) : 0;
            cur[tid] = 0;
        }
        __syncthreads();
        #pragma unroll
        for (int i = 0; i < PCHUNK / TPB; ++i) {
            int e = e0 + tid + i * TPB;
            if (e < P.E) {
                int d = P.dst[e];
                int bkt = d >> BSHIFT;
                int pos = base[bkt] + atomicAdd(&cur[bkt], 1);
                if (pos < BCAP2)
                    P.pairs[bkt * BCAP2 + pos] = ((unsigned)(d & 255) << 17) | (unsigned)P.src[e];
            }
        }
        __syncthreads();
    }
    {   // wswz + pooled zero: reversed block ownership so idle (high) blocks do it
        int wtot = 6 * 16384 + P.nPooled4;
        int rb = grid - 1 - b;
        for (int i = rb * TPB + tid; i < wtot; i += grid * TPB) {
            if (i < 6 * 16384) {
                int m = i >> 14;
                int im = i & 16383;
                int j = im & 7;
                int l = (im >> 3) & 63;
                int k0 = (im >> 9) & 7;
                int ct = (im >> 12) & 3;
                int k = k0 * 16 + ((l >> 5) << 3) + j;
                int nn = ct * 32 + (l & 31);
                P.wdst[m][im] = f2bf(P.wsrc[m][k * CH + nn]);
            } else {
                ((uint4*)P.pooled)[i - 6 * 16384] = make_uint4(0, 0, 0, 0);
            }
        }
    }
    gg.sync();

    // ---------------- phase A: CSR build || x -> bf16
    int nCsr = (P.N + 255) >> BSHIFT;
    for (int cb = b; cb < nCsr; cb += grid) {
        int* bsm  = smem;                    // [NB2]
        int* ldeg = smem + NB2;              // [256]
        int* s0   = smem + NB2 + 256;        // [256]
        int* s1   = s0 + 256;                // [256]
        int* lexc = s1 + 256;                // [256]
        int* lcur = lexc + 256;              // [256]
        int* lcsr = lcur + 256;              // [BCAP2]
        int node0 = cb << BSHIFT;
        int nLocal = min(256, P.N - node0);

        bsm[tid] = P.bucketCnt[tid];
        __syncthreads();
        for (int off = 1; off < NB2; off <<= 1) {
            int t = (tid >= off) ? bsm[tid - off] : 0;
            __syncthreads();
            bsm[tid] += t;
            __syncthreads();
        }
        int cnt = min(P.bucketCnt[cb], BCAP2);
        int gbase = bsm[cb] - P.bucketCnt[cb];

        if (tid < 256) ldeg[tid] = 0;
        __syncthreads();
        for (int i = tid; i < cnt; i += TPB)
            atomicAdd(&ldeg[P.pairs[cb * BCAP2 + i] >> 17], 1);
        __syncthreads();

        if (tid < 256) s0[tid] = ldeg[tid];
        __syncthreads();
        int* sp = s0; int* dp = s1;
        for (int off = 1; off < 256; off <<= 1) {
            if (tid < 256) dp[tid] = sp[tid] + ((tid >= off) ? sp[tid - off] : 0);
            __syncthreads();
            int* t = sp; sp = dp; dp = t;
        }
        if (tid < 256) {
            int ex = sp[tid] - ldeg[tid];
            lexc[tid] = ex;
            lcur[tid] = ex;
        }
        __syncthreads();

        for (int i = tid; i < cnt; i += TPB) {
            unsigned w = P.pairs[cb * BCAP2 + i];
            int ppos = atomicAdd(&lcur[w >> 17], 1);
            lcsr[ppos] = (int)(w & 0x1ffffu);
        }
        __syncthreads();

        for (int i = tid; i < cnt; i += TPB) P.csr[gbase + i] = lcsr[i];
        for (int i = tid; i < nLocal; i += TPB) P.offs[node0 + i] = gbase + lexc[i];
        if (tid == 0 && node0 + nLocal == P.N) P.offs[P.N] = gbase + cnt;
        __syncthreads();
    }
    {   // x -> bf16: idle blocks if grid > nCsr, else everyone after csr
        int i0, stride;
        if (grid > nCsr) {
            if (b >= nCsr) { i0 = (b - nCsr) * TPB + tid; stride = (grid - nCsr) * TPB; }
            else           { i0 = P.n4; stride = 1; }
        } else {
            i0 = b * TPB + tid; stride = grid * TPB;
        }
        for (int i = i0; i < P.n4; i += stride) {
            float4 v = P.x4[i];
            uint2 o;
            o.x = (unsigned)f2bf(v.x) | ((unsigned)f2bf(v.y) << 16);
            o.y = (unsigned)f2bf(v.z) | ((unsigned)f2bf(v.w) << 16);
            ((uint2*)P.xb)[i] = o;
        }
    }
    gg.sync();

    // ---------------- phases B/C/D: three fused GIN layers
    unsigned short* zs = (unsigned short*)smem;
    int NT = (P.N + FBM - 1) / FBM;

    int wv = tid >> 6;         // 0..7
    int lane = tid & 63;
    int l31 = lane & 31;
    int kh = lane >> 5;
    int rt = wv & 1;           // 2 row tiles of 32
    int ct = wv >> 1;          // 4 col tiles of 32
    int arow = rt * 32 + l31;

    for (int l = 0; l < 3; ++l) {
        const uint4* h4 = (l == 0) ? (const uint4*)P.xb
                        : (l == 1) ? (const uint4*)P.hA : (const uint4*)P.hB;
        unsigned short* hout = (l == 0) ? P.hA : P.hB;
        const unsigned short* w1s = P.wdst[2 * l];
        const unsigned short* w2s = P.wdst[2 * l + 1];
        const float* b1 = P.b1v[l];
        const float* b2 = P.b2v[l];
        int relu = (l < 2) ? 1 : 0;
        int pool = (l == 2) ? 1 : 0;

        for (int t = b; t < NT; t += grid) {
            int row0 = t * FBM;

            // gather: z = h[node] + sum h[src] (fp32 accum -> bf16 in LDS)
            {
                int gl = tid & 15;
                int grp = tid >> 4;
                #pragma unroll
                for (int it2 = 0; it2 < 2; ++it2) {
                    int rr = grp + 32 * it2;
                    int node = row0 + rr;
                    unsigned o0 = 0, o1 = 0, o2 = 0, o3 = 0;
                    if (node < P.N) {
                        int beg = P.offs[node], end = P.offs[node + 1];
                        f32x2 a[4];
                        uint4 self = h4[node * 16 + gl];
                        a[0] = bf2(self.x);
                        a[1] = bf2(self.y);
                        a[2] = bf2(self.z);
                        a[3] = bf2(self.w);
                        int e = beg;
                        for (; e + 4 <= end; e += 4) {
                            int s0i = P.csr[e], s1i = P.csr[e + 1], s2i = P.csr[e + 2], s3i = P.csr[e + 3];
                            uint4 v0 = h4[s0i * 16 + gl];
                            uint4 v1 = h4[s1i * 16 + gl];
                            uint4 v2 = h4[s2i * 16 + gl];
                            uint4 v3 = h4[s3i * 16 + gl];
                            acc8(a, v0); acc8(a, v1); acc8(a, v2); acc8(a, v3);
                        }
                        for (; e < end; ++e) {
                            uint4 v = h4[P.csr[e] * 16 + gl];
                            acc8(a, v);
                        }
                        o0 = (unsigned)f2bf(a[0][0]) | ((unsigned)f2bf(a[0][1]) << 16);
                        o1 = (unsigned)f2bf(a[1][0]) | ((unsigned)f2bf(a[1][1]) << 16);
                        o2 = (unsigned)f2bf(a[2][0]) | ((unsigned)f2bf(a[2][1]) << 16);
                        o3 = (unsigned)f2bf(a[3][0]) | ((unsigned)f2bf(a[3][1]) << 16);
                    }
                    *(uint2*)&zs[rr * PQ2 + gl * 8]     = make_uint2(o0, o1);
                    *(uint2*)&zs[rr * PQ2 + gl * 8 + 4] = make_uint2(o2, o3);
                }
            }
            __syncthreads();

            // matmul 1: t = relu(z @ w1 + b1)
            f32x16 acc;
            {
                float bv = b1[ct * 32 + l31];
                #pragma unroll
                for (int r = 0; r < 16; ++r) acc[r] = bv;
            }
            #pragma unroll
            for (int k0 = 0; k0 < 8; ++k0) {
                short8 afr;
                {
                    short4v lo = *(const short4v*)&zs[arow * PQ2 + k0 * 16 + kh * 8];
                    short4v hi = *(const short4v*)&zs[arow * PQ2 + k0 * 16 + kh * 8 + 4];
                    afr = (short8){lo[0], lo[1], lo[2], lo[3], hi[0], hi[1], hi[2], hi[3]};
                }
                short8 bfr = *(const short8*)&w1s[(((ct * 8 + k0) * 64) + lane) * 8];
                acc = __builtin_amdgcn_mfma_f32_32x32x16_bf16(afr, bfr, acc, 0, 0, 0);
            }
            __syncthreads();

            #pragma unroll
            for (int reg = 0; reg < 16; ++reg) {
                int crow = (reg & 3) + 8 * (reg >> 2) + 4 * kh;
                zs[(rt * 32 + crow) * PQ2 + ct * 32 + l31] = f2bf(fmaxf(acc[reg], 0.f));
            }
            __syncthreads();

            // matmul 2: h = t @ w2 + b2 [+ relu]
            {
                float bv = b2[ct * 32 + l31];
                #pragma unroll
                for (int r = 0; r < 16; ++r) acc[r] = bv;
            }
            #pragma unroll
            for (int k0 = 0; k0 < 8; ++k0) {
                short8 afr;
                {
                    short4v lo = *(const short4v*)&zs[arow * PQ2 + k0 * 16 + kh * 8];
                    short4v hi = *(const short4v*)&zs[arow * PQ2 + k0 * 16 + kh * 8 + 4];
                    afr = (short8){lo[0], lo[1], lo[2], lo[3], hi[0], hi[1], hi[2], hi[3]};
                }
                short8 bfr = *(const short8*)&w2s[(((ct * 8 + k0) * 64) + lane) * 8];
                acc = __builtin_amdgcn_mfma_f32_32x32x16_bf16(afr, bfr, acc, 0, 0, 0);
            }
            __syncthreads();

            #pragma unroll
            for (int reg = 0; reg < 16; ++reg) {
                int crow = (reg & 3) + 8 * (reg >> 2) + 4 * kh;
                float v = acc[reg];
                if (relu) v = fmaxf(v, 0.f);
                zs[(rt * 32 + crow) * PQ2 + ct * 32 + l31] = f2bf(v);
            }
            __syncthreads();

            if (!pool) {
                for (int i = tid; i < FBM * 16; i += TPB) {
                    int r = i >> 4, c = i & 15;
                    int row = row0 + r;
                    if (row < P.N) {
                        uint2 a2 = *(const uint2*)&zs[r * PQ2 + c * 8];
                        uint2 b2u = *(const uint2*)&zs[r * PQ2 + c * 8 + 4];
                        ((uint4*)hout)[row * 16 + c] = make_uint4(a2.x, a2.y, b2u.x, b2u.y);
                    }
                }
            } else {
                int c2 = tid & 63;
                int rs = tid >> 6;
                float a0 = 0.f, a1 = 0.f;
                int prevg = -1;
                #pragma unroll
                for (int i = 0; i < FBM / 8; ++i) {
                    int r = rs + 8 * i;
                    int row = row0 + r;
                    if (row >= P.N) break;
                    int g = P.batch[row];
                    if (g != prevg) {
                        if (prevg >= 0) {
                            atomicAdd(&P.pooled[prevg * CH + 2 * c2], a0);
                            atomicAdd(&P.pooled[prevg * CH + 2 * c2 + 1], a1);
                        }
                        prevg = g; a0 = 0.f; a1 = 0.f;
                    }
                    unsigned v = *(const unsigned*)&zs[r * PQ2 + c2 * 2];
                    a0 += bflo(v); a1 += bfhi(v);
                }
                if (prevg >= 0) {
                    atomicAdd(&P.pooled[prevg * CH + 2 * c2], a0);
                    atomicAdd(&P.pooled[prevg * CH + 2 * c2 + 1], a1);
                }
            }
            __syncthreads();   // zs reused by next tile's gather
        }
        gg.sync();
    }

    // ---------------- phase E: final linear
    for (int gb = b; gb < P.nGraphs; gb += grid) {
        float* pl = (float*)smem;
        if (tid < CH) pl[tid] = P.pooled[gb * CH + tid];
        __syncthreads();
        if (tid < OUTC) {
            float a = P.lin_b[tid];
            #pragma unroll 16
            for (int c = 0; c < CH; ++c) a = fmaf(pl[c], P.lin_w[c * OUTC + tid], a);
            P.out[gb * OUTC + tid] = a;
        }
        __syncthreads();
    }
}

// ---------------------------------------------------------------- launch

static inline size_t aln(size_t x) { return (x + 255) & ~size_t(255); }

extern "C" void kernel_launch(void* const* d_in, const int* in_sizes, int n_in,
                              void* d_out, int out_size, void* d_ws, size_t ws_size,
                              hipStream_t stream) {
    const float* x      = (const float*)d_in[0];
    const int*   ei     = (const int*)d_in[1];
    const int*   batch  = (const int*)d_in[2];
    const float* w1[3]  = {(const float*)d_in[3], (const float*)d_in[7],  (const float*)d_in[11]};
    const float* b1[3]  = {(const float*)d_in[4], (const float*)d_in[8],  (const float*)d_in[12]};
    const float* w2[3]  = {(const float*)d_in[5], (const float*)d_in[9],  (const float*)d_in[13]};
    const float* b2[3]  = {(const float*)d_in[6], (const float*)d_in[10], (const float*)d_in[14]};
    const float* lin_w  = (const float*)d_in[15];
    const float* lin_b  = (const float*)d_in[16];
    float* out = (float*)d_out;

    int E = in_sizes[1] / 2;
    int N = in_sizes[2];
    int n_graphs = out_size / OUTC;
    const int* src = ei;
    const int* dst = ei + E;

    char* p = (char*)d_ws;
    int* bucketCnt  = (int*)p; p += aln(NB2 * 4);
    unsigned* pairs = (unsigned*)p; p += aln((size_t)NB2 * BCAP2 * 4);
    int* offs       = (int*)p; p += aln((size_t)(N + 1) * 4);
    int* csr        = (int*)p; p += aln((size_t)E * 4);
    unsigned short* xb = (unsigned short*)p; p += aln((size_t)N * CH * 2);
    unsigned short* hA = (unsigned short*)p; p += aln((size_t)N * CH * 2);
    unsigned short* hB = (unsigned short*)p; p += aln((size_t)N * CH * 2);
    float* pooled = (float*)p; p += aln((size_t)n_graphs * CH * 4);
    unsigned short* wt[6];
    for (int i = 0; i < 6; ++i) { wt[i] = (unsigned short*)p; p += aln((size_t)CH * CH * 2); }
    (void)ws_size; (void)n_in;

    hipMemsetAsync(bucketCnt, 0, NB2 * 4, stream);

    MegaP P;
    P.src = src; P.dst = dst; P.E = E;
    P.bucketCnt = bucketCnt; P.pairs = pairs;
    P.offs = offs; P.csr = csr; P.N = N;
    P.x4 = (const float4*)x; P.xb = xb; P.n4 = N * CH / 4;
    for (int l = 0; l < 3; ++l) {
        P.wsrc[2 * l] = w1[l];     P.wdst[2 * l] = wt[2 * l];
        P.wsrc[2 * l + 1] = w2[l]; P.wdst[2 * l + 1] = wt[2 * l + 1];
        P.b1v[l] = b1[l]; P.b2v[l] = b2[l];
    }
    P.hA = hA; P.hB = hB;
    P.batch = batch; P.pooled = pooled; P.nPooled4 = n_graphs * CH / 4;
    P.nGraphs = n_graphs; P.lin_w = lin_w; P.lin_b = lin_b; P.out = out;

    int maxB = 0;
    hipOccupancyMaxActiveBlocksPerMultiprocessor(&maxB, mega_kernel, TPB, 0);
    if (maxB < 1) maxB = 1;
    long long grid = (long long)maxB * 256;   // 256 CUs on MI355X
    if (grid > 2048) grid = 2048;
    if (grid < 256) grid = 256;

    void* kargs[] = { (void*)&P };
    hipLaunchCooperativeKernel(reinterpret_cast<void*>(mega_kernel),
                               dim3((unsigned)grid), dim3(TPB), kargs, 0, stream);
}

// Round 11
// 623.906 us; speedup vs baseline: 1.3991x; 1.3991x over previous
//
#include <hip/hip_runtime.h>

#define CH 128
#define OUTC 10
#define NB2 512           // buckets (dst >> 8): 256-node buckets
#define BSHIFT 8
#define BCAP2 5120        // per-bucket pair capacity (avg ~4096, +16 sigma margin)
#define PCHUNK 8192       // edges per partition block (R11: 4x fewer bucketCnt line-RMWs)
#define PQ2 132           // LDS pitch in bf16 (dword stride 66 -> 2-way bank alias = free)
#define FBM 64            // rows per fused-layer block

typedef __attribute__((ext_vector_type(8))) short short8;
typedef __attribute__((ext_vector_type(4))) short short4v;
typedef __attribute__((ext_vector_type(16))) float f32x16;
typedef __attribute__((ext_vector_type(2))) float f32x2;

// ---------------------------------------------------------------- helpers

__device__ inline unsigned short f2bf(float f) {
    unsigned u = __builtin_bit_cast(unsigned, f);
    u += 0x7fffu + ((u >> 16) & 1u);   // RNE
    return (unsigned short)(u >> 16);
}
__device__ inline float bflo(unsigned u) { return __builtin_bit_cast(float, u << 16); }
__device__ inline float bfhi(unsigned u) { return __builtin_bit_cast(float, u & 0xffff0000u); }

// packed bf16 pair -> f32x2 (lshl / and, then one packed add on the consumer)
__device__ inline f32x2 bf2(unsigned u) {
    return (f32x2){__builtin_bit_cast(float, u << 16),
                   __builtin_bit_cast(float, u & 0xffff0000u)};
}

__device__ inline void acc8(f32x2* a, const uint4& v) {
    a[0] += bf2(v.x);
    a[1] += bf2(v.y);
    a[2] += bf2(v.z);
    a[3] += bf2(v.w);
}

// ---------------------------------------------------------------- mega prep: edge partition + x->bf16 + w-swizzle + pooled zero

struct WPtrs { const float* s[6]; unsigned short* d[6]; };

__global__ void prep_part_kernel(const int* __restrict__ src, const int* __restrict__ dst,
                                 int* __restrict__ bucketCnt, unsigned* __restrict__ pairs, int E,
                                 int nPartBlk,
                                 const float4* __restrict__ x4, uint2* __restrict__ xb, int n4,
                                 int nConvBlk, WPtrs p,
                                 uint4* __restrict__ pooled4, int nPooled4) {
    __shared__ int hist[NB2];
    __shared__ int base[NB2];
    __shared__ int cur[NB2];
    int tid = threadIdx.x;   // 256
    int b = blockIdx.x;

    if (b < nPartBlk) {
        int e0 = b * PCHUNK;
        hist[tid] = 0; hist[tid + 256] = 0;
        __syncthreads();
        for (int i = 0; i < PCHUNK / 256; ++i) {
            int e = e0 + tid + i * 256;
            if (e < E) atomicAdd(&hist[dst[e] >> BSHIFT], 1);
        }
        __syncthreads();
        #pragma unroll
        for (int k = 0; k < 2; ++k) {
            int t2 = tid + k * 256;
            int c = hist[t2];
            base[t2] = (c > 0) ? atomicAdd(&bucketCnt[t2], c) : 0;
            cur[t2] = 0;
        }
        __syncthreads();
        for (int i = 0; i < PCHUNK / 256; ++i) {
            int e = e0 + tid + i * 256;
            if (e < E) {
                int d = dst[e];
                int bkt = d >> BSHIFT;
                int pos = base[bkt] + atomicAdd(&cur[bkt], 1);
                if (pos < BCAP2)
                    pairs[bkt * BCAP2 + pos] = ((unsigned)(d & 255) << 17) | (unsigned)src[e];
            }
        }
    } else if (b < nPartBlk + nConvBlk) {
        int i = (b - nPartBlk) * 256 + tid;
        if (i < n4) {
            float4 v = x4[i];
            uint2 o;
            o.x = (unsigned)f2bf(v.x) | ((unsigned)f2bf(v.y) << 16);
            o.y = (unsigned)f2bf(v.z) | ((unsigned)f2bf(v.w) << 16);
            xb[i] = o;
        }
    } else if (b < nPartBlk + nConvBlk + 384) {
        int bb = b - nPartBlk - nConvBlk;  // 0..383
        int m = bb >> 6;                   // matrix 0..5
        int i = (bb & 63) * 256 + tid;     // 0..16383
        int j = i & 7;
        int l = (i >> 3) & 63;
        int k0 = (i >> 9) & 7;
        int ct = (i >> 12) & 3;
        int k = k0 * 16 + ((l >> 5) << 3) + j;
        int nn = ct * 32 + (l & 31);
        p.d[m][i] = f2bf(p.s[m][k * CH + nn]);
    } else {
        int i = (b - nPartBlk - nConvBlk - 384) * 256 + tid;
        if (i < nPooled4) pooled4[i] = make_uint4(0, 0, 0, 0);
    }
}

// ---------------------------------------------------------------- CSR build (self-scans bucket counts)

__launch_bounds__(512)
__global__ void build_csr_kernel(const unsigned* __restrict__ pairs, const int* __restrict__ bucketCnt,
                                 int* __restrict__ offs, int* __restrict__ csr, int N) {
    __shared__ int bsm[NB2];
    __shared__ int ldeg[256];
    __shared__ int s0[256], s1[256];
    __shared__ int lexc[256];
    __shared__ int lcur[256];
    __shared__ int lcsr[BCAP2];

    int b = blockIdx.x;
    int node0 = b << BSHIFT;
    if (node0 >= N) return;
    int nLocal = min(256, N - node0);
    int tid = threadIdx.x;   // 512

    bsm[tid] = bucketCnt[tid];
    __syncthreads();
    for (int off = 1; off < NB2; off <<= 1) {
        int t = (tid >= off) ? bsm[tid - off] : 0;
        __syncthreads();
        bsm[tid] += t;
        __syncthreads();
    }
    int cnt = min(bucketCnt[b], BCAP2);
    int gbase = bsm[b] - bucketCnt[b];

    if (tid < 256) ldeg[tid] = 0;
    __syncthreads();
    for (int i = tid; i < cnt; i += 512)
        atomicAdd(&ldeg[pairs[b * BCAP2 + i] >> 17], 1);
    __syncthreads();

    if (tid < 256) s0[tid] = ldeg[tid];
    __syncthreads();
    int* sp = s0; int* dp = s1;
    for (int off = 1; off < 256; off <<= 1) {
        if (tid < 256) dp[tid] = sp[tid] + ((tid >= off) ? sp[tid - off] : 0);
        __syncthreads();
        int* t = sp; sp = dp; dp = t;
    }
    if (tid < 256) {
        int ex = sp[tid] - ldeg[tid];
        lexc[tid] = ex;
        lcur[tid] = ex;
    }
    __syncthreads();

    for (int i = tid; i < cnt; i += 512) {
        unsigned w = pairs[b * BCAP2 + i];
        int ppos = atomicAdd(&lcur[w >> 17], 1);
        lcsr[ppos] = (int)(w & 0x1ffffu);
    }
    __syncthreads();

    for (int i = tid; i < cnt; i += 512) csr[gbase + i] = lcsr[i];
    for (int i = tid; i < nLocal; i += 512) offs[node0 + i] = gbase + lexc[i];
    if (tid == 0 && node0 + nLocal == N) offs[N] = gbase + cnt;
}

// ---------------------------------------------------------------- fused GIN layer: gather -> LDS -> MFMA MLP -> write | pool(+final)
// R9's best-measured configuration (76 us, VGPR 28, occ ~66%). Gather is at
// the per-XCD L2-fill wall (2.5-2.7 TB/s raw; insensitive across 9 configs).
// R11: POOL kernel also runs the final linear on the LAST block to finish
// (threadfence + done-counter), removing the 4th dispatch.

template <int L, int RELU, int POOL>
__launch_bounds__(512)
__global__ void fused_gin_kernel(const uint4* __restrict__ h4,
                                 const int* __restrict__ offs, const int* __restrict__ csr,
                                 const unsigned short* __restrict__ w1s, const float* __restrict__ b1,
                                 const unsigned short* __restrict__ w2s, const float* __restrict__ b2,
                                 unsigned short* __restrict__ hout,
                                 const int* __restrict__ batch, float* __restrict__ pooled,
                                 int n,
                                 int* __restrict__ doneCnt, int nGraphs,
                                 const float* __restrict__ lin_w, const float* __restrict__ lin_b,
                                 float* __restrict__ out) {
    __shared__ __align__(16) unsigned short zs[FBM * PQ2];   // 16.9 KB
    __shared__ int lastFlag;

    int tid = threadIdx.x;
    int row0 = blockIdx.x * FBM;

    // ---- gather phase: z = h[node] + sum h[src], fp32 accum -> bf16 into LDS
    {
        int gl = tid & 15;
        int grp = tid >> 4;    // 0..31
        #pragma unroll
        for (int it = 0; it < 2; ++it) {
            int rr = grp + 32 * it;
            int node = row0 + rr;
            unsigned o0 = 0, o1 = 0, o2 = 0, o3 = 0;
            if (node < n) {
                int beg = offs[node], end = offs[node + 1];
                f32x2 a[4];
                uint4 self = h4[node * 16 + gl];
                a[0] = bf2(self.x);
                a[1] = bf2(self.y);
                a[2] = bf2(self.z);
                a[3] = bf2(self.w);
                int e = beg;
                int elim = beg + ((end - beg) & ~3);   // end of full batches
                if (e < elim) {
                    int s0 = csr[e], s1 = csr[e + 1], s2 = csr[e + 2], s3 = csr[e + 3];
                    for (; e + 8 <= elim; e += 4) {
                        uint4 v0 = h4[s0 * 16 + gl];
                        uint4 v1 = h4[s1 * 16 + gl];
                        uint4 v2 = h4[s2 * 16 + gl];
                        uint4 v3 = h4[s3 * 16 + gl];
                        int t0 = csr[e + 4], t1 = csr[e + 5], t2 = csr[e + 6], t3 = csr[e + 7];
                        acc8(a, v0); acc8(a, v1); acc8(a, v2); acc8(a, v3);
                        s0 = t0; s1 = t1; s2 = t2; s3 = t3;
                    }
                    {
                        uint4 v0 = h4[s0 * 16 + gl];
                        uint4 v1 = h4[s1 * 16 + gl];
                        uint4 v2 = h4[s2 * 16 + gl];
                        uint4 v3 = h4[s3 * 16 + gl];
                        acc8(a, v0); acc8(a, v1); acc8(a, v2); acc8(a, v3);
                        e += 4;
                    }
                }
                for (; e < end; ++e) {
                    uint4 v = h4[csr[e] * 16 + gl];
                    acc8(a, v);
                }
                o0 = (unsigned)f2bf(a[0][0]) | ((unsigned)f2bf(a[0][1]) << 16);
                o1 = (unsigned)f2bf(a[1][0]) | ((unsigned)f2bf(a[1][1]) << 16);
                o2 = (unsigned)f2bf(a[2][0]) | ((unsigned)f2bf(a[2][1]) << 16);
                o3 = (unsigned)f2bf(a[3][0]) | ((unsigned)f2bf(a[3][1]) << 16);
            }
            *(uint2*)&zs[rr * PQ2 + gl * 8]     = make_uint2(o0, o1);
            *(uint2*)&zs[rr * PQ2 + gl * 8 + 4] = make_uint2(o2, o3);
        }
    }
    __syncthreads();

    int wv = tid >> 6;         // 0..7
    int lane = tid & 63;
    int l31 = lane & 31;
    int kh = lane >> 5;
    int rt = wv & 1;           // 2 row tiles of 32
    int ct = wv >> 1;          // 4 col tiles of 32
    int arow = rt * 32 + l31;

    // ---- matmul 1: t = relu(z @ w1 + b1)
    f32x16 acc;
    {
        float bv = b1[ct * 32 + l31];
        #pragma unroll
        for (int r = 0; r < 16; ++r) acc[r] = bv;
    }
    #pragma unroll
    for (int k0 = 0; k0 < 8; ++k0) {
        short8 afr;
        {
            short4v lo = *(const short4v*)&zs[arow * PQ2 + k0 * 16 + kh * 8];
            short4v hi = *(const short4v*)&zs[arow * PQ2 + k0 * 16 + kh * 8 + 4];
            afr = (short8){lo[0], lo[1], lo[2], lo[3], hi[0], hi[1], hi[2], hi[3]};
        }
        short8 bfr = *(const short8*)&w1s[(((ct * 8 + k0) * 64) + lane) * 8];
        acc = __builtin_amdgcn_mfma_f32_32x32x16_bf16(afr, bfr, acc, 0, 0, 0);
    }
    __syncthreads();

    #pragma unroll
    for (int reg = 0; reg < 16; ++reg) {
        int crow = (reg & 3) + 8 * (reg >> 2) + 4 * kh;
        zs[(rt * 32 + crow) * PQ2 + ct * 32 + l31] = f2bf(fmaxf(acc[reg], 0.f));
    }
    __syncthreads();

    // ---- matmul 2: h = t @ w2 + b2 [+ relu]
    {
        float bv = b2[ct * 32 + l31];
        #pragma unroll
        for (int r = 0; r < 16; ++r) acc[r] = bv;
    }
    #pragma unroll
    for (int k0 = 0; k0 < 8; ++k0) {
        short8 afr;
        {
            short4v lo = *(const short4v*)&zs[arow * PQ2 + k0 * 16 + kh * 8];
            short4v hi = *(const short4v*)&zs[arow * PQ2 + k0 * 16 + kh * 8 + 4];
            afr = (short8){lo[0], lo[1], lo[2], lo[3], hi[0], hi[1], hi[2], hi[3]};
        }
        short8 bfr = *(const short8*)&w2s[(((ct * 8 + k0) * 64) + lane) * 8];
        acc = __builtin_amdgcn_mfma_f32_32x32x16_bf16(afr, bfr, acc, 0, 0, 0);
    }
    __syncthreads();

    #pragma unroll
    for (int reg = 0; reg < 16; ++reg) {
        int crow = (reg & 3) + 8 * (reg >> 2) + 4 * kh;
        float v = acc[reg];
        if (RELU) v = fmaxf(v, 0.f);
        zs[(rt * 32 + crow) * PQ2 + ct * 32 + l31] = f2bf(v);
    }
    __syncthreads();

    if (!POOL) {
        for (int i = tid; i < FBM * 16; i += 512) {
            int r = i >> 4, c = i & 15;
            int row = row0 + r;
            if (row < n) {
                uint2 a2 = *(const uint2*)&zs[r * PQ2 + c * 8];
                uint2 b2v = *(const uint2*)&zs[r * PQ2 + c * 8 + 4];
                ((uint4*)hout)[row * 16 + c] = make_uint4(a2.x, a2.y, b2v.x, b2v.y);
            }
        }
    } else {
        // pool epilogue from LDS tile (batch sorted)
        int c2 = tid & 63;      // uint column (ch 2*c2, 2*c2+1)
        int rs = tid >> 6;      // 0..7
        float a0 = 0.f, a1 = 0.f;
        int prevg = -1;
        #pragma unroll
        for (int i = 0; i < FBM / 8; ++i) {
            int r = rs + 8 * i;
            int row = row0 + r;
            if (row >= n) break;
            int g = batch[row];
            if (g != prevg) {
                if (prevg >= 0) {
                    atomicAdd(&pooled[prevg * CH + 2 * c2], a0);
                    atomicAdd(&pooled[prevg * CH + 2 * c2 + 1], a1);
                }
                prevg = g; a0 = 0.f; a1 = 0.f;
            }
            unsigned v = *(const unsigned*)&zs[r * PQ2 + c2 * 2];
            a0 += bflo(v); a1 += bfhi(v);
        }
        if (prevg >= 0) {
            atomicAdd(&pooled[prevg * CH + 2 * c2], a0);
            atomicAdd(&pooled[prevg * CH + 2 * c2 + 1], a1);
        }

        // ---- last-block final linear (folds the 4th dispatch)
        __threadfence();
        if (tid == 0) {
            unsigned old = atomicAdd((unsigned*)doneCnt, 1u);
            lastFlag = (old == (unsigned)(gridDim.x - 1)) ? 1 : 0;
        }
        __syncthreads();
        if (lastFlag) {             // block-uniform branch: barriers inside are legal
            __threadfence();        // acquire: all pooled atomics visible
            float* lwS = (float*)zs;    // reuse LDS (5.12 KB of 16.9)
            for (int i = tid; i < CH * OUTC; i += 512) lwS[i] = lin_w[i];
            __syncthreads();
            for (int g = tid; g < nGraphs; g += 512) {
                float a[OUTC];
                #pragma unroll
                for (int o = 0; o < OUTC; ++o) a[o] = lin_b[o];
                for (int c = 0; c < CH; ++c) {
                    float pv = pooled[g * CH + c];
                    #pragma unroll
                    for (int o = 0; o < OUTC; ++o)
                        a[o] = fmaf(pv, lwS[c * OUTC + o], a[o]);
                }
                #pragma unroll
                for (int o = 0; o < OUTC; ++o) out[g * OUTC + o] = a[o];
            }
        }
    }
}

// ---------------------------------------------------------------- launch

static inline size_t aln(size_t x) { return (x + 255) & ~size_t(255); }

extern "C" void kernel_launch(void* const* d_in, const int* in_sizes, int n_in,
                              void* d_out, int out_size, void* d_ws, size_t ws_size,
                              hipStream_t stream) {
    const float* x      = (const float*)d_in[0];
    const int*   ei     = (const int*)d_in[1];
    const int*   batch  = (const int*)d_in[2];
    const float* w1[3]  = {(const float*)d_in[3], (const float*)d_in[7],  (const float*)d_in[11]};
    const float* b1[3]  = {(const float*)d_in[4], (const float*)d_in[8],  (const float*)d_in[12]};
    const float* w2[3]  = {(const float*)d_in[5], (const float*)d_in[9],  (const float*)d_in[13]};
    const float* b2[3]  = {(const float*)d_in[6], (const float*)d_in[10], (const float*)d_in[14]};
    const float* lin_w  = (const float*)d_in[15];
    const float* lin_b  = (const float*)d_in[16];
    float* out = (float*)d_out;

    int E = in_sizes[1] / 2;
    int N = in_sizes[2];
    int n_graphs = out_size / OUTC;
    const int* src = ei;
    const int* dst = ei + E;

    char* p = (char*)d_ws;
    int* bucketCnt  = (int*)p; p += aln(NB2 * 4 + 64);   // +done counter
    int* doneCnt    = bucketCnt + NB2;
    unsigned* pairs = (unsigned*)p; p += aln((size_t)NB2 * BCAP2 * 4);
    int* offs       = (int*)p; p += aln((size_t)(N + 1) * 4);
    int* csr        = (int*)p; p += aln((size_t)E * 4);
    unsigned short* xb = (unsigned short*)p; p += aln((size_t)N * CH * 2);
    unsigned short* hA = (unsigned short*)p; p += aln((size_t)N * CH * 2);
    unsigned short* hB = (unsigned short*)p; p += aln((size_t)N * CH * 2);
    float* pooled = (float*)p; p += aln((size_t)n_graphs * CH * 4);
    unsigned short* wt[6];
    for (int i = 0; i < 6; ++i) { wt[i] = (unsigned short*)p; p += aln((size_t)CH * CH * 2); }
    (void)ws_size; (void)n_in;

    // bucketCnt + done counter must be zero before partition blocks run
    hipMemsetAsync(bucketCnt, 0, NB2 * 4 + 64, stream);

    // mega-prep: partition + convert x + swizzle weights + zero pooled
    int n4 = N * CH / 4;
    int nConvBlk = (n4 + 255) / 256;
    int nPartBlk = (E + PCHUNK - 1) / PCHUNK;
    int nPooled4 = n_graphs * CH / 4;
    int nZeroBlk = (nPooled4 + 255) / 256;
    WPtrs wp;
    for (int l = 0; l < 3; ++l) {
        wp.s[2 * l] = w1[l];     wp.d[2 * l] = wt[2 * l];
        wp.s[2 * l + 1] = w2[l]; wp.d[2 * l + 1] = wt[2 * l + 1];
    }
    prep_part_kernel<<<nPartBlk + nConvBlk + 384 + nZeroBlk, 256, 0, stream>>>(
        src, dst, bucketCnt, pairs, E, nPartBlk,
        (const float4*)x, (uint2*)xb, n4, nConvBlk, wp,
        (uint4*)pooled, nPooled4);

    build_csr_kernel<<<NB2, 512, 0, stream>>>(pairs, bucketCnt, offs, csr, N);

    int fblk = (N + FBM - 1) / FBM;

    // three fused GIN layers (layer 3 embeds the final linear via last-block)
    fused_gin_kernel<0, 1, 0><<<fblk, 512, 0, stream>>>((const uint4*)xb, offs, csr,
        wt[0], b1[0], wt[1], b2[0], hA, batch, pooled, N,
        nullptr, 0, nullptr, nullptr, nullptr);
    fused_gin_kernel<1, 1, 0><<<fblk, 512, 0, stream>>>((const uint4*)hA, offs, csr,
        wt[2], b1[1], wt[3], b2[1], hB, batch, pooled, N,
        nullptr, 0, nullptr, nullptr, nullptr);
    fused_gin_kernel<2, 0, 1><<<fblk, 512, 0, stream>>>((const uint4*)hB, offs, csr,
        wt[4], b1[2], wt[5], b2[2], (unsigned short*)nullptr, batch, pooled, N,
        doneCnt, n_graphs, lin_w, lin_b, out);
}